// Round 3
// baseline (451.780 us; speedup 1.0000x reference)
//
#include <hip/hip_runtime.h>
#include <hip/hip_bf16.h>

// Problem constants
#define Bb 8
#define Nn 4096
#define Mm 256
#define Dd 1024
#define Hh 16
#define HDd 64
#define Ss 4352   // N + M
#define INNERd 1024
#define SPLIT 8

typedef __attribute__((ext_vector_type(4))) float f32x4;
typedef __attribute__((ext_vector_type(8))) short short8;
typedef __attribute__((ext_vector_type(4))) int int4v;

__device__ __forceinline__ float bf2f(short u) {
  union { unsigned int i; float f; } c;
  c.i = ((unsigned int)(unsigned short)u) << 16;
  return c.f;
}
__device__ __forceinline__ short f2bf(float f) {
  union { float f; unsigned int i; } c; c.f = f;
  unsigned int x = c.i;
  x += 0x7fff + ((x >> 16) & 1);   // RNE
  return (short)(x >> 16);
}
__device__ __forceinline__ void gload16(const short* g, short* l) {
  __builtin_amdgcn_global_load_lds(
      (const __attribute__((address_space(1))) void*)g,
      (__attribute__((address_space(3))) void*)l, 16, 0, 0);
}

// ---------------- LayerNorm (row of 1024 f32) -> bf16 ----------------
__global__ void ln_bf16_kernel(const float* __restrict__ src,
                               const float* __restrict__ w,
                               const float* __restrict__ bvec,
                               short* __restrict__ dst) {
  int row = blockIdx.x;
  const float4* x4 = (const float4*)(src + (size_t)row * Dd);
  int t = threadIdx.x;                       // 256 threads, 4 f32 each
  float4 v = x4[t];
  float s  = v.x + v.y + v.z + v.w;
  float ss = v.x*v.x + v.y*v.y + v.z*v.z + v.w*v.w;
#pragma unroll
  for (int o = 1; o < 64; o <<= 1) {
    s  += __shfl_xor(s,  o, 64);
    ss += __shfl_xor(ss, o, 64);
  }
  __shared__ float red[8];
  int wv = t >> 6;
  if ((t & 63) == 0) { red[wv] = s; red[4 + wv] = ss; }
  __syncthreads();
  float tot  = red[0] + red[1] + red[2] + red[3];
  float tot2 = red[4] + red[5] + red[6] + red[7];
  float mean = tot * (1.0f / Dd);
  float var  = tot2 * (1.0f / Dd) - mean * mean;
  float inv  = rsqrtf(var + 1e-5f);
  float4 wv4 = ((const float4*)w)[t];
  float4 bv4 = ((const float4*)bvec)[t];
  short4 o4;
  o4.x = f2bf((v.x - mean) * inv * wv4.x + bv4.x);
  o4.y = f2bf((v.y - mean) * inv * wv4.y + bv4.y);
  o4.z = f2bf((v.z - mean) * inv * wv4.z + bv4.z);
  o4.w = f2bf((v.w - mean) * inv * wv4.w + bv4.w);
  *(short4*)(dst + (size_t)row * Dd + t * 4) = o4;
}

// ------------- weight convert f32[K][N] -> bf16 transposed [N][K] -------------
__global__ void wconv_kernel(const float* __restrict__ src, short* __restrict__ dst,
                             int K, int Ncol) {
  __shared__ float tile[32][33];
  int bx = blockIdx.x, by = blockIdx.y;
  int tx = threadIdx.x, ty = threadIdx.y;
#pragma unroll
  for (int i = 0; i < 32; i += 8)
    tile[ty + i][tx] = src[(size_t)(by * 32 + ty + i) * Ncol + bx * 32 + tx];
  __syncthreads();
#pragma unroll
  for (int i = 0; i < 32; i += 8)
    dst[(size_t)(bx * 32 + ty + i) * K + by * 32 + tx] = f2bf(tile[tx][ty + i]);
}

// =====================================================================
// Deep-pipelined GEMM: 256x128 tile, BK=64, 8 waves (4M x 2N), K=1024.
// 3-deep LDS ring (144 KiB), counted vmcnt(12) in steady state (T3+T4),
// 8-chunk XOR swizzle at 128B row stride (T2, conflict-free),
// chunked XCD swizzle, col-fastest ordering (T1), setprio around MFMA (T5).
// MODE 2: A=xn -> k/v scatter with fused 2D RoPE on k (d<32)
// MODE 4: A=lnr, Bt=[Wq|Wkv] -> q (scaled) / k_l / v_l scatter at s=N+m
// =====================================================================
template<int MODE>
__device__ __forceinline__ void stage_tile(const short* __restrict__ A,
                                           const short* __restrict__ Bt,
                                           short* As, short* Bs,
                                           int brow, int bcol, int kt, int t) {
#pragma unroll
  for (int u = 0; u < 4; u++) {              // A: 256 rows x 8 chunks = 2048
    int cid = t + u * 512;
    int r = cid >> 3, pc = cid & 7;
    gload16(A + (size_t)(brow + r) * 1024 + kt + ((pc ^ (r & 7)) * 8), As + cid * 8);
  }
#pragma unroll
  for (int u = 0; u < 2; u++) {              // B: 128 rows x 8 chunks = 1024
    int cid = t + u * 512;
    int r = cid >> 3, pc = cid & 7;
    gload16(Bt + (size_t)(bcol + r) * 1024 + kt + ((pc ^ (r & 7)) * 8), Bs + cid * 8);
  }
}

template<int MODE>
__global__ __launch_bounds__(512) void gemm_big_kernel(
    const short* __restrict__ A, const short* __restrict__ Bt,
    short* __restrict__ qdst, short* __restrict__ kdst, short* __restrict__ vdst,
    int ncp) {
  __shared__ __align__(16) short As[3][256 * 64];
  __shared__ __align__(16) short Bs[3][128 * 64];
  __shared__ float ctab[(MODE == 2) ? 1024 : 1];
  int t = threadIdx.x;
  int wave = t >> 6, lane = t & 63;
  int wm = wave >> 1, wn = wave & 1;
  int lr = lane & 15, lg = lane >> 4;
  // XCD-chunked swizzle (grid divisible by 8), column-panel fastest
  int nwg = gridDim.x;
  int cpx = nwg >> 3;
  int swz = (blockIdx.x & 7) * cpx + (blockIdx.x >> 3);
  int colp = swz % ncp, rowp = swz / ncp;
  int brow = rowp * 256, bcol = colp * 128;
  if (MODE == 2) {
    for (int i = t; i < 512; i += 512) {
      int pos = i >> 3, f = i & 7;
      float ang = (float)pos * exp2f(-1.6609640474436813f * (float)f);
      ctab[i] = cosf(ang);
      ctab[512 + i] = sinf(ang);
    }
  }
  f32x4 acc[4][4] = {};
  // prologue: stage tiles 0,1 (12 loads/wave outstanding)
  stage_tile<MODE>(A, Bt, As[0], Bs[0], brow, bcol, 0, t);
  stage_tile<MODE>(A, Bt, As[1], Bs[1], brow, bcol, 64, t);
  for (int tt = 0; tt < 16; tt++) {
    __builtin_amdgcn_sched_barrier(0);
    if (tt < 14) {
      // stage tile tt+2 into ring slot freed two iterations ago
      stage_tile<MODE>(A, Bt, As[(tt + 2) % 3], Bs[(tt + 2) % 3],
                       brow, bcol, (tt + 2) * 64, t);
      asm volatile("s_waitcnt vmcnt(12)" ::: "memory");  // tile tt landed; 12 in flight
    } else if (tt == 14) {
      asm volatile("s_waitcnt vmcnt(6)" ::: "memory");
    } else {
      asm volatile("s_waitcnt vmcnt(0)" ::: "memory");
    }
    __builtin_amdgcn_s_barrier();            // all waves' tile-tt loads visible
    __builtin_amdgcn_sched_barrier(0);
    const short* pa = As[tt % 3];
    const short* pb = Bs[tt % 3];
#pragma unroll
    for (int ks = 0; ks < 2; ks++) {
      short8 a[4], b[4];
#pragma unroll
      for (int i = 0; i < 4; i++) {
        int ra = wm * 64 + i * 16 + lr;
        a[i] = *(const short8*)(pa + ra * 64 + (((ks * 4 + lg) ^ (ra & 7)) * 8));
        int rb = wn * 64 + i * 16 + lr;
        b[i] = *(const short8*)(pb + rb * 64 + (((ks * 4 + lg) ^ (rb & 7)) * 8));
      }
      __builtin_amdgcn_s_setprio(1);
#pragma unroll
      for (int mi = 0; mi < 4; mi++)
#pragma unroll
        for (int ni = 0; ni < 4; ni++)
          acc[mi][ni] = __builtin_amdgcn_mfma_f32_16x16x32_bf16(a[mi], b[ni], acc[mi][ni], 0, 0, 0);
      __builtin_amdgcn_s_setprio(0);
    }
    __builtin_amdgcn_sched_barrier(0);
    __builtin_amdgcn_s_barrier();            // all waves done reading slot tt%3
  }
  // ---------------- epilogue ----------------
  int cbase = bcol + wn * 64;                // wave's 64-col block = one head slice
  if (MODE == 2) {
    bool kreg = (bcol < 1024);
    short* dstp = kreg ? kdst : vdst;
    int h = (cbase & 1023) >> 6;
#pragma unroll
    for (int mi = 0; mi < 4; mi++)
#pragma unroll
      for (int rr = 0; rr < 4; rr++) {
        int row = brow + wm * 64 + mi * 16 + lg * 4 + rr;
        int bb = row >> 12, n = row & 4095;
        float v[4];
#pragma unroll
        for (int ni = 0; ni < 4; ni++) v[ni] = acc[mi][ni][rr];
        if (kreg) {                           // 2D RoPE on d<32 of this head
          int pos = (lr & 8) ? (n & 63) : (n >> 6);
          float cs = ctab[pos * 8 + (lr & 7)];
          float sn = ctab[512 + pos * 8 + (lr & 7)];
          float v0 = v[0], v1 = v[1];
          v[0] = v0 * cs - v1 * sn;
          v[1] = v1 * cs + v0 * sn;
        }
        size_t rb = (((size_t)(bb * Hh + h)) * Ss + n) * HDd;
#pragma unroll
        for (int ni = 0; ni < 4; ni++)
          dstp[rb + ni * 16 + lr] = f2bf(v[ni]);
      }
  } else {
#pragma unroll
    for (int mi = 0; mi < 4; mi++)
#pragma unroll
      for (int rr = 0; rr < 4; rr++) {
        int row = brow + wm * 64 + mi * 16 + lg * 4 + rr;
        int bb = row >> 8, m = row & 255;
        float v[4];
#pragma unroll
        for (int ni = 0; ni < 4; ni++) v[ni] = acc[mi][ni][rr];
        if (cbase < 1024) {                  // q, scaled by HD^-0.5
          int h = cbase >> 6;
          size_t rb = (((size_t)(bb * Hh + h)) * Mm + m) * HDd;
#pragma unroll
          for (int ni = 0; ni < 4; ni++)
            qdst[rb + ni * 16 + lr] = f2bf(v[ni] * 0.125f);
        } else if (cbase < 2048) {           // k_l at s = N + m
          int h = (cbase - 1024) >> 6;
          size_t rb = (((size_t)(bb * Hh + h)) * Ss + (Nn + m)) * HDd;
#pragma unroll
          for (int ni = 0; ni < 4; ni++)
            kdst[rb + ni * 16 + lr] = f2bf(v[ni]);
        } else {                             // v_l at s = N + m
          int h = (cbase - 2048) >> 6;
          size_t rb = (((size_t)(bb * Hh + h)) * Ss + (Nn + m)) * HDd;
#pragma unroll
          for (int ni = 0; ni < 4; ni++)
            vdst[rb + ni * 16 + lr] = f2bf(v[ni]);
        }
      }
  }
}

// ---------------- small GEMM (out proj): C[M][N] fp32 = A bf16 * Bt^T ----------------
__global__ void gemm_out_kernel(const short* __restrict__ A, const short* __restrict__ Bt,
                                float* __restrict__ C, int Ncols, int K) {
  __shared__ __align__(16) short Asm[128 * 32];
  __shared__ __align__(16) short Bsm[128 * 32];
  int t = threadIdx.x;
  int wave = t >> 6, lane = t & 63;
  int wm = (wave >> 1) * 64, wn = (wave & 1) * 64;
  int brow = blockIdx.y * 128, bcol = blockIdx.x * 128;
  int lr = lane & 15, lg = lane >> 4;
  f32x4 acc[4][4] = {};
  for (int kt = 0; kt < K; kt += 32) {
    __syncthreads();
#pragma unroll
    for (int u = 0; u < 2; u++) {
      int cid = t + u * 256;
      int r = cid >> 2, c = cid & 3;
      int cl = c ^ (r & 3);
      gload16(A + (size_t)(brow + r) * K + kt + cl * 8, Asm + cid * 8);
      gload16(Bt + (size_t)(bcol + r) * K + kt + cl * 8, Bsm + cid * 8);
    }
    __syncthreads();
    short8 a[4], b[4];
#pragma unroll
    for (int i = 0; i < 4; i++) {
      int ra = wm + i * 16 + lr;
      a[i] = *(const short8*)(Asm + ra * 32 + (lg ^ (ra & 3)) * 8);
      int rb = wn + i * 16 + lr;
      b[i] = *(const short8*)(Bsm + rb * 32 + (lg ^ (rb & 3)) * 8);
    }
#pragma unroll
    for (int mi = 0; mi < 4; mi++)
#pragma unroll
      for (int ni = 0; ni < 4; ni++)
        acc[mi][ni] = __builtin_amdgcn_mfma_f32_16x16x32_bf16(a[mi], b[ni], acc[mi][ni], 0, 0, 0);
  }
#pragma unroll
  for (int mi = 0; mi < 4; mi++)
#pragma unroll
    for (int ni = 0; ni < 4; ni++)
#pragma unroll
      for (int r = 0; r < 4; r++) {
        int row = brow + wm + mi * 16 + lg * 4 + r;
        int col = bcol + wn + ni * 16 + lr;
        C[(size_t)row * Ncols + col] = acc[mi][ni][r];
      }
}

// ---------------- flash attention, KV-split: blocks = (b,h)*SPLIT, 8 waves x 32 q-rows ----
__global__ __launch_bounds__(512) void attn_kernel(const short* __restrict__ qb,
                            const short* __restrict__ kb,
                            const short* __restrict__ vb,
                            float* __restrict__ pO,
                            float* __restrict__ pMS) {
  __shared__ __align__(16) short Ksm[64 * 64];       // [key][d], chunk^=(key&7)
  __shared__ __align__(16) short Vsm[64 * 64];       // [d][key], chunk^=(d&7)
  __shared__ __align__(16) short Psm[8][32 * 64];    // per-wave P, chunk^=(row&7)
  int blk = blockIdx.x;
  int sp = blk & (SPLIT - 1), bh = blk >> 3;
  int t = threadIdx.x, wave = t >> 6, lane = t & 63;
  int lr = lane & 15, lg = lane >> 4;
  int q0 = wave * 32;
  const short* qptr = qb + (size_t)bh * Mm * HDd;
  short8 qf[2][2];
#pragma unroll
  for (int mi = 0; mi < 2; mi++)
#pragma unroll
    for (int ks = 0; ks < 2; ks++)
      qf[mi][ks] = *(const short8*)(qptr + (size_t)(q0 + mi * 16 + lr) * HDd + ks * 32 + lg * 8);
  f32x4 accO[2][4] = {};
  float mrow[2][4], srow[2][4];
#pragma unroll
  for (int mi = 0; mi < 2; mi++)
#pragma unroll
    for (int r = 0; r < 4; r++) { mrow[mi][r] = -1e30f; srow[mi][r] = 0.0f; }
  const short* kbase = kb + (size_t)bh * Ss * HDd;
  const short* vbase = vb + (size_t)bh * Ss * HDd;
  short* P = &Psm[wave][0];
  int tile0 = (sp * 68) >> 3, tile1 = ((sp + 1) * 68) >> 3;
  for (int tt = tile0; tt < tile1; tt++) {
    int kt = tt * 64;
    __syncthreads();
    {
      int r = t >> 3, c = t & 7;             // 512 threads, one 16B chunk each
      int cl = c ^ (r & 7);
      gload16(kbase + (size_t)(kt + r) * HDd + cl * 8, Ksm + t * 8);
      short8 vv = *(const short8*)(vbase + (size_t)(kt + r) * HDd + c * 8);
#pragma unroll
      for (int e = 0; e < 8; e++) {
        int d = c * 8 + e;
        Vsm[d * 64 + (((r >> 3) ^ (d & 7)) * 8) + (r & 7)] = vv[e];
      }
    }
    __syncthreads();
    // S = Q @ K^T
    f32x4 accS[2][4] = {};
#pragma unroll
    for (int ks = 0; ks < 2; ks++) {
      short8 bk[4];
#pragma unroll
      for (int ji = 0; ji < 4; ji++) {
        int j = ji * 16 + lr;
        int cd = ks * 4 + lg;
        bk[ji] = *(const short8*)(Ksm + j * 64 + ((cd ^ (j & 7)) * 8));
      }
#pragma unroll
      for (int mi = 0; mi < 2; mi++)
#pragma unroll
        for (int ji = 0; ji < 4; ji++)
          accS[mi][ji] = __builtin_amdgcn_mfma_f32_16x16x32_bf16(qf[mi][ks], bk[ji], accS[mi][ji], 0, 0, 0);
    }
    // online softmax (fp32, 16-lane reductions)
#pragma unroll
    for (int mi = 0; mi < 2; mi++)
#pragma unroll
      for (int r = 0; r < 4; r++) {
        float mx = fmaxf(fmaxf(accS[mi][0][r], accS[mi][1][r]),
                         fmaxf(accS[mi][2][r], accS[mi][3][r]));
#pragma unroll
        for (int o = 1; o < 16; o <<= 1) mx = fmaxf(mx, __shfl_xor(mx, o, 64));
        float mnew = fmaxf(mrow[mi][r], mx);
        float corr = __expf(mrow[mi][r] - mnew);
        mrow[mi][r] = mnew;
        float rs = 0.0f;
#pragma unroll
        for (int ji = 0; ji < 4; ji++) {
          float pv = __expf(accS[mi][ji][r] - mnew);
          accS[mi][ji][r] = pv;
          rs += pv;
        }
#pragma unroll
        for (int o = 1; o < 16; o <<= 1) rs += __shfl_xor(rs, o, 64);
        srow[mi][r] = srow[mi][r] * corr + rs;
#pragma unroll
        for (int di = 0; di < 4; di++) accO[mi][di][r] *= corr;
      }
    // P -> LDS (wave-private, swizzled), bf16
#pragma unroll
    for (int mi = 0; mi < 2; mi++)
#pragma unroll
      for (int ji = 0; ji < 4; ji++)
#pragma unroll
        for (int r = 0; r < 4; r++) {
          int row = mi * 16 + lg * 4 + r;
          int col = ji * 16 + lr;
          P[row * 64 + (((col >> 3) ^ (row & 7)) * 8) + (col & 7)] = f2bf(accS[mi][ji][r]);
        }
    // O += P @ V
#pragma unroll
    for (int ks = 0; ks < 2; ks++) {
      short8 pa[2], bvv[4];
#pragma unroll
      for (int mi = 0; mi < 2; mi++) {
        int row = mi * 16 + lr;
        int ck = ks * 4 + lg;
        pa[mi] = *(const short8*)(P + row * 64 + ((ck ^ (row & 7)) * 8));
      }
#pragma unroll
      for (int di = 0; di < 4; di++) {
        int d = di * 16 + lr;
        int ck = ks * 4 + lg;
        bvv[di] = *(const short8*)(Vsm + d * 64 + ((ck ^ (d & 7)) * 8));
      }
#pragma unroll
      for (int mi = 0; mi < 2; mi++)
#pragma unroll
        for (int di = 0; di < 4; di++)
          accO[mi][di] = __builtin_amdgcn_mfma_f32_16x16x32_bf16(pa[mi], bvv[di], accO[mi][di], 0, 0, 0);
    }
  }
  // write split partials (unnormalized O in fp32 + per-row m,s)
  size_t base = (size_t)blk * 256;
#pragma unroll
  for (int mi = 0; mi < 2; mi++)
#pragma unroll
    for (int r = 0; r < 4; r++) {
      int m = q0 + mi * 16 + lg * 4 + r;
      if (lr == 0) {
        pMS[(base + m) * 2]     = mrow[mi][r];
        pMS[(base + m) * 2 + 1] = srow[mi][r];
      }
#pragma unroll
      for (int di = 0; di < 4; di++)
        pO[(base + m) * 64 + di * 16 + lr] = accO[mi][di][r];
    }
}

// ---------------- combine the SPLIT partials ----------------
__global__ void attn_combine(const float* __restrict__ pO, const float* __restrict__ pMS,
                             short* __restrict__ ob) {
  int t = threadIdx.x;
  int row = blockIdx.x * 4 + (t >> 6);       // over B*H*M = 32768
  int bh = row >> 8, m = row & 255;
  int d = t & 63;
  float mv[SPLIT], sv[SPLIT];
  float mx = -1e30f;
#pragma unroll
  for (int s = 0; s < SPLIT; s++) {
    size_t rbase = ((size_t)(bh * SPLIT + s) * 256 + m);
    mv[s] = pMS[rbase * 2];
    sv[s] = pMS[rbase * 2 + 1];
    mx = fmaxf(mx, mv[s]);
  }
  float den = 0.0f, acc = 0.0f;
#pragma unroll
  for (int s = 0; s < SPLIT; s++) {
    float wgt = __expf(mv[s] - mx);
    den += wgt * sv[s];
    acc += wgt * pO[((size_t)(bh * SPLIT + s) * 256 + m) * 64 + d];
  }
  int b = bh >> 4, h = bh & 15;
  ob[((size_t)(b * Mm + m)) * INNERd + h * HDd + d] = f2bf(acc / den);
}

extern "C" void kernel_launch(void* const* d_in, const int* in_sizes, int n_in,
                              void* d_out, int out_size, void* d_ws, size_t ws_size,
                              hipStream_t stream) {
  const float* x    = (const float*)d_in[0];
  const float* lat  = (const float*)d_in[1];
  const float* lnxw = (const float*)d_in[2];
  const float* lnxb = (const float*)d_in[3];
  const float* lnlw = (const float*)d_in[4];
  const float* lnlb = (const float*)d_in[5];
  const float* Wq   = (const float*)d_in[6];
  const float* Wkv  = (const float*)d_in[7];
  const float* Wo   = (const float*)d_in[8];
  char* w = (char*)d_ws;
  const size_t MB = 1048576;
  short* Wqkvt = (short*)(w + 0 * MB);     // 6 MB: rows 0-1023 = Wq^T, 1024-3071 = Wkv^T
  short* Wot   = (short*)(w + 6 * MB);     // 2 MB
  short* xn    = (short*)(w + 8 * MB);     // 64 MB (reused as pO by attn)
  short* lnr   = (short*)(w + 72 * MB);    // 4 MB (reused as pMS by attn)
  short* qbuf  = (short*)(w + 76 * MB);    // 4 MB
  short* kbuf  = (short*)(w + 80 * MB);    // 68 MB
  short* vbuf  = (short*)(w + 148 * MB);   // 68 MB
  short* aout  = (short*)(w + 216 * MB);   // 4 MB
  float* pO    = (float*)(w + 8 * MB);     // 64 MB, aliases xn (dead by attn time)
  float* pMS   = (float*)(w + 72 * MB);    // 2 MB, aliases lnr (dead by attn time)

  ln_bf16_kernel<<<dim3(Bb * Nn), dim3(256), 0, stream>>>(x, lnxw, lnxb, xn);
  ln_bf16_kernel<<<dim3(Bb * Mm), dim3(256), 0, stream>>>(lat, lnlw, lnlb, lnr);
  wconv_kernel<<<dim3(32, 32), dim3(32, 8), 0, stream>>>(Wq, Wqkvt, 1024, 1024);
  wconv_kernel<<<dim3(64, 32), dim3(32, 8), 0, stream>>>(Wkv, Wqkvt + (size_t)1024 * 1024, 1024, 2048);
  wconv_kernel<<<dim3(32, 32), dim3(32, 8), 0, stream>>>(Wo, Wot, 1024, 1024);
  // kv_x = xn @ Wkv -> scatter k/v, fused RoPE on k d<32.  grid: 128 rowp x 16 colp
  gemm_big_kernel<2><<<dim3(2048), dim3(512), 0, stream>>>(
      xn, Wqkvt + (size_t)1024 * 1024, (short*)nullptr, kbuf, vbuf, 16);
  // fused q + kv_l = lnr @ [Wq|Wkv] -> q (scaled), k_l/v_l at s=N+m.  grid: 8 x 24
  gemm_big_kernel<4><<<dim3(192), dim3(512), 0, stream>>>(
      lnr, Wqkvt, qbuf, kbuf, vbuf, 24);
  // flash attention with KV-split 8 + combine
  attn_kernel<<<dim3(Bb * Hh * SPLIT), dim3(512), 0, stream>>>(qbuf, kbuf, vbuf, pO, pMS);
  attn_combine<<<dim3(Bb * Hh * Mm / 4), dim3(256), 0, stream>>>(pO, pMS, aout);
  // out = aout @ Wo (fp32)
  gemm_out_kernel<<<dim3(8, 16), dim3(256), 0, stream>>>(aout, Wot, (float*)d_out, 1024, 1024);
}

// Round 4
// 417.572 us; speedup vs baseline: 1.0819x; 1.0819x over previous
//
#include <hip/hip_runtime.h>
#include <hip/hip_bf16.h>

// Problem constants
#define Bb 8
#define Nn 4096
#define Mm 256
#define Dd 1024
#define Hh 16
#define HDd 64
#define Ss 4352   // N + M
#define INNERd 1024
#define SPLIT 8

typedef __attribute__((ext_vector_type(4))) float f32x4;
typedef __attribute__((ext_vector_type(8))) short short8;
typedef __attribute__((ext_vector_type(4))) int int4v;

__device__ __forceinline__ float bf2f(short u) {
  union { unsigned int i; float f; } c;
  c.i = ((unsigned int)(unsigned short)u) << 16;
  return c.f;
}
__device__ __forceinline__ short f2bf(float f) {
  union { float f; unsigned int i; } c; c.f = f;
  unsigned int x = c.i;
  x += 0x7fff + ((x >> 16) & 1);   // RNE
  return (short)(x >> 16);
}
__device__ __forceinline__ void gload16(const short* g, short* l) {
  __builtin_amdgcn_global_load_lds(
      (const __attribute__((address_space(1))) void*)g,
      (__attribute__((address_space(3))) void*)l, 16, 0, 0);
}

// ---------------- LayerNorm (row of 1024 f32) -> bf16 ----------------
__global__ void ln_bf16_kernel(const float* __restrict__ src,
                               const float* __restrict__ w,
                               const float* __restrict__ bvec,
                               short* __restrict__ dst) {
  int row = blockIdx.x;
  const float4* x4 = (const float4*)(src + (size_t)row * Dd);
  int t = threadIdx.x;                       // 256 threads, 4 f32 each
  float4 v = x4[t];
  float s  = v.x + v.y + v.z + v.w;
  float ss = v.x*v.x + v.y*v.y + v.z*v.z + v.w*v.w;
#pragma unroll
  for (int o = 1; o < 64; o <<= 1) {
    s  += __shfl_xor(s,  o, 64);
    ss += __shfl_xor(ss, o, 64);
  }
  __shared__ float red[8];
  int wv = t >> 6;
  if ((t & 63) == 0) { red[wv] = s; red[4 + wv] = ss; }
  __syncthreads();
  float tot  = red[0] + red[1] + red[2] + red[3];
  float tot2 = red[4] + red[5] + red[6] + red[7];
  float mean = tot * (1.0f / Dd);
  float var  = tot2 * (1.0f / Dd) - mean * mean;
  float inv  = rsqrtf(var + 1e-5f);
  float4 wv4 = ((const float4*)w)[t];
  float4 bv4 = ((const float4*)bvec)[t];
  short4 o4;
  o4.x = f2bf((v.x - mean) * inv * wv4.x + bv4.x);
  o4.y = f2bf((v.y - mean) * inv * wv4.y + bv4.y);
  o4.z = f2bf((v.z - mean) * inv * wv4.z + bv4.z);
  o4.w = f2bf((v.w - mean) * inv * wv4.w + bv4.w);
  *(short4*)(dst + (size_t)row * Dd + t * 4) = o4;
}

// ------------- weight convert f32[K][N] -> bf16 transposed [N][K] -------------
__global__ void wconv_kernel(const float* __restrict__ src, short* __restrict__ dst,
                             int K, int Ncol) {
  __shared__ float tile[32][33];
  int bx = blockIdx.x, by = blockIdx.y;
  int tx = threadIdx.x, ty = threadIdx.y;
#pragma unroll
  for (int i = 0; i < 32; i += 8)
    tile[ty + i][tx] = src[(size_t)(by * 32 + ty + i) * Ncol + bx * 32 + tx];
  __syncthreads();
#pragma unroll
  for (int i = 0; i < 32; i += 8)
    dst[(size_t)(bx * 32 + ty + i) * K + by * 32 + tx] = f2bf(tile[tx][ty + i]);
}

// =====================================================================
// 8-phase deep-pipelined GEMM: 256x256 tile, BK=64 (2 K-halves of 32),
// 8 waves (2M x 4N), K=1024 fixed, per-wave output 128x64 (acc[8][4]).
// LDS [2 buf][2 khalf][256 rows][32 cols] per operand = 128 KiB total.
// Phases per K-tile: P0 (ks0, m0-3), P1 (ks0, m4-7), P2 (ks1, m0-3),
// P3 (ks1, m4-7). b-frags loaded once per ks, reused across 2 phases.
// Staging: P0/P1 -> K1(tt+1) into other buf; P2/P3 -> K0(tt+2) into
// just-freed khalf0 of current buf. Counted vmcnt(8) at end-P1/end-P3
// (4 half-tiles = 8 loads/thread always in flight; tail 8,4,0).
// Swizzle: 64B LDS rows, chunk ^= (row>>1)&3 (pre-swizzled global src,
// same XOR on ds_read) -> 2 lanes/bank-slot per 16-lane quad = free.
// MODE 2: A=xn -> k/v scatter with fused 2D RoPE on k (d<32)
// MODE 4: A=lnr, Bt=[Wq|Wkv] -> q (scaled) / k_l / v_l at s=N+m
// =====================================================================
__device__ __forceinline__ void stage_half(const short* __restrict__ src,
                                           short* dst, int rowbase, int kcol, int t) {
#pragma unroll
  for (int u = 0; u < 2; u++) {
    int cid = t + u * 512;
    int r = cid >> 2, c = cid & 3;
    gload16(src + (size_t)(rowbase + r) * 1024 + kcol + ((c ^ ((r >> 1) & 3)) * 8),
            dst + cid * 8);
  }
}

#define DS_B(pb) do { _Pragma("unroll") \
  for (int j = 0; j < 4; j++) { int rbw = wn * 64 + j * 16 + lr; \
    bfr[j] = *(const short8*)((pb) + rbw * 32 + ((lg ^ ((rbw >> 1) & 3)) * 8)); } } while (0)
#define DS_A(pa, mbase) do { _Pragma("unroll") \
  for (int i = 0; i < 4; i++) { int raw = wm * 128 + ((mbase) + i) * 16 + lr; \
    afr[i] = *(const short8*)((pa) + raw * 32 + ((lg ^ ((raw >> 1) & 3)) * 8)); } } while (0)
#define MFMA16(mbase) do { __builtin_amdgcn_s_setprio(1); _Pragma("unroll") \
  for (int i = 0; i < 4; i++) { _Pragma("unroll") \
    for (int j = 0; j < 4; j++) \
      acc[(mbase) + i][j] = __builtin_amdgcn_mfma_f32_16x16x32_bf16(afr[i], bfr[j], acc[(mbase) + i][j], 0, 0, 0); } \
  __builtin_amdgcn_s_setprio(0); } while (0)
#define ENDPHASE do { __builtin_amdgcn_sched_barrier(0); \
  __builtin_amdgcn_s_barrier(); __builtin_amdgcn_sched_barrier(0); } while (0)

template<int MODE>
__global__ __launch_bounds__(512, 2) void gemm8_kernel(
    const short* __restrict__ A, const short* __restrict__ Bt,
    short* __restrict__ qdst, short* __restrict__ kdst, short* __restrict__ vdst,
    int ncp) {
  __shared__ __align__(16) short Al[2][2][256 * 32];   // [buf][khalf][row*32+col]
  __shared__ __align__(16) short Bl[2][2][256 * 32];
  __shared__ float ctab[(MODE == 2) ? 1024 : 1];
  int t = threadIdx.x;
  int wave = t >> 6, lane = t & 63;
  int wm = wave >> 2, wn = wave & 3;                   // 2M x 4N
  int lr = lane & 15, lg = lane >> 4;
  // XCD-chunked swizzle (grid divisible by 8), column-panel fastest
  int nwg = gridDim.x;
  int cpx = nwg >> 3;
  int swz = (blockIdx.x & 7) * cpx + (blockIdx.x >> 3);
  int colp = swz % ncp, rowp = swz / ncp;
  int brow = rowp * 256, bcol = colp * 256;
  if (MODE == 2) {
    if (t < 512) {
      int pos = t >> 3, f = t & 7;
      float ang = (float)pos * exp2f(-1.6609640474436813f * (float)f);
      ctab[t] = cosf(ang);
      ctab[512 + t] = sinf(ang);
    }
  }
  f32x4 acc[8][4] = {};
  // ---- prologue: K0(0), K1(0), K0(1) for both operands (12 loads/thread)
  stage_half(A,  &Al[0][0][0], brow, 0,  t);
  stage_half(Bt, &Bl[0][0][0], bcol, 0,  t);
  stage_half(A,  &Al[0][1][0], brow, 32, t);
  stage_half(Bt, &Bl[0][1][0], bcol, 32, t);
  stage_half(A,  &Al[1][0][0], brow, 64, t);
  stage_half(Bt, &Bl[1][0][0], bcol, 64, t);
  asm volatile("s_waitcnt vmcnt(8)" ::: "memory");     // K0(0) landed
  __builtin_amdgcn_s_barrier();
  __builtin_amdgcn_sched_barrier(0);

  for (int tt = 0; tt < 16; ++tt) {
    int cb = tt & 1, nb = cb ^ 1;
    short8 afr[4], bfr[4];
    // ---- P0: ks=0, m-frags 0-3
    DS_B(&Bl[cb][0][0]);
    DS_A(&Al[cb][0][0], 0);
    if (tt < 15) stage_half(A, &Al[nb][1][0], brow, (tt + 1) * 64 + 32, t);
    MFMA16(0);
    ENDPHASE;
    // ---- P1: ks=0, m-frags 4-7 (b-frags reused)
    DS_A(&Al[cb][0][0], 4);
    if (tt < 15) stage_half(Bt, &Bl[nb][1][0], bcol, (tt + 1) * 64 + 32, t);
    MFMA16(4);
    if (tt < 15) { asm volatile("s_waitcnt vmcnt(8)" ::: "memory"); }
    else         { asm volatile("s_waitcnt vmcnt(0)" ::: "memory"); }
    ENDPHASE;                                          // K1(tt) now visible
    // ---- P2: ks=1, m-frags 0-3
    DS_B(&Bl[cb][1][0]);
    DS_A(&Al[cb][1][0], 0);
    if (tt < 14) stage_half(A, &Al[cb][0][0], brow, (tt + 2) * 64, t);
    MFMA16(0);
    ENDPHASE;
    // ---- P3: ks=1, m-frags 4-7
    DS_A(&Al[cb][1][0], 4);
    if (tt < 14) stage_half(Bt, &Bl[cb][0][0], bcol, (tt + 2) * 64, t);
    MFMA16(4);
    if (tt < 14)       { asm volatile("s_waitcnt vmcnt(8)" ::: "memory"); }
    else if (tt == 14) { asm volatile("s_waitcnt vmcnt(4)" ::: "memory"); }
    ENDPHASE;                                          // K0(tt+1) now visible
  }
  // ---------------- epilogue ----------------
  int cbase = bcol + wn * 64;                          // wave's 64-col block = one head
  if (MODE == 2) {
    bool kreg = (bcol < 1024);
    short* dstp = kreg ? kdst : vdst;
    int h = (cbase & 1023) >> 6;
#pragma unroll
    for (int i = 0; i < 8; i++)
#pragma unroll
      for (int rr = 0; rr < 4; rr++) {
        int row = brow + wm * 128 + i * 16 + lg * 4 + rr;
        int bb = row >> 12, n = row & 4095;
        float v[4];
#pragma unroll
        for (int j = 0; j < 4; j++) v[j] = acc[i][j][rr];
        if (kreg) {                                    // 2D RoPE on d<32
          int pos = (lr & 8) ? (n & 63) : (n >> 6);
          float cs = ctab[pos * 8 + (lr & 7)];
          float sn = ctab[512 + pos * 8 + (lr & 7)];
          float v0 = v[0], v1 = v[1];
          v[0] = v0 * cs - v1 * sn;
          v[1] = v1 * cs + v0 * sn;
        }
        size_t rb = (((size_t)(bb * Hh + h)) * Ss + n) * HDd;
#pragma unroll
        for (int j = 0; j < 4; j++)
          dstp[rb + j * 16 + lr] = f2bf(v[j]);
      }
  } else {
#pragma unroll
    for (int i = 0; i < 8; i++)
#pragma unroll
      for (int rr = 0; rr < 4; rr++) {
        int row = brow + wm * 128 + i * 16 + lg * 4 + rr;
        int bb = row >> 8, m = row & 255;
        float v[4];
#pragma unroll
        for (int j = 0; j < 4; j++) v[j] = acc[i][j][rr];
        if (cbase < 1024) {                            // q, scaled HD^-0.5
          int h = cbase >> 6;
          size_t rb = (((size_t)(bb * Hh + h)) * Mm + m) * HDd;
#pragma unroll
          for (int j = 0; j < 4; j++)
            qdst[rb + j * 16 + lr] = f2bf(v[j] * 0.125f);
        } else if (cbase < 2048) {                     // k_l at s = N + m
          int h = (cbase - 1024) >> 6;
          size_t rb = (((size_t)(bb * Hh + h)) * Ss + (Nn + m)) * HDd;
#pragma unroll
          for (int j = 0; j < 4; j++)
            kdst[rb + j * 16 + lr] = f2bf(v[j]);
        } else {                                       // v_l at s = N + m
          int h = (cbase - 2048) >> 6;
          size_t rb = (((size_t)(bb * Hh + h)) * Ss + (Nn + m)) * HDd;
#pragma unroll
          for (int j = 0; j < 4; j++)
            vdst[rb + j * 16 + lr] = f2bf(v[j]);
        }
      }
  }
}

// ---------------- small GEMM (out proj): C[M][N] fp32 = A bf16 * Bt^T ----------------
__global__ void gemm_out_kernel(const short* __restrict__ A, const short* __restrict__ Bt,
                                float* __restrict__ C, int Ncols, int K) {
  __shared__ __align__(16) short Asm[128 * 32];
  __shared__ __align__(16) short Bsm[128 * 32];
  int t = threadIdx.x;
  int wave = t >> 6, lane = t & 63;
  int wm = (wave >> 1) * 64, wn = (wave & 1) * 64;
  int brow = blockIdx.y * 128, bcol = blockIdx.x * 128;
  int lr = lane & 15, lg = lane >> 4;
  f32x4 acc[4][4] = {};
  for (int kt = 0; kt < K; kt += 32) {
    __syncthreads();
#pragma unroll
    for (int u = 0; u < 2; u++) {
      int cid = t + u * 256;
      int r = cid >> 2, c = cid & 3;
      int cl = c ^ (r & 3);
      gload16(A + (size_t)(brow + r) * K + kt + cl * 8, Asm + cid * 8);
      gload16(Bt + (size_t)(bcol + r) * K + kt + cl * 8, Bsm + cid * 8);
    }
    __syncthreads();
    short8 a[4], b[4];
#pragma unroll
    for (int i = 0; i < 4; i++) {
      int ra = wm + i * 16 + lr;
      a[i] = *(const short8*)(Asm + ra * 32 + (lg ^ (ra & 3)) * 8);
      int rb = wn + i * 16 + lr;
      b[i] = *(const short8*)(Bsm + rb * 32 + (lg ^ (rb & 3)) * 8);
    }
#pragma unroll
    for (int mi = 0; mi < 4; mi++)
#pragma unroll
      for (int ni = 0; ni < 4; ni++)
        acc[mi][ni] = __builtin_amdgcn_mfma_f32_16x16x32_bf16(a[mi], b[ni], acc[mi][ni], 0, 0, 0);
  }
#pragma unroll
  for (int mi = 0; mi < 4; mi++)
#pragma unroll
    for (int ni = 0; ni < 4; ni++)
#pragma unroll
      for (int r = 0; r < 4; r++) {
        int row = brow + wm + mi * 16 + lg * 4 + r;
        int col = bcol + wn + ni * 16 + lr;
        C[(size_t)row * Ncols + col] = acc[mi][ni][r];
      }
}

// ---------------- flash attention, KV-split: blocks = (b,h)*SPLIT, 8 waves x 32 q-rows ----
__global__ __launch_bounds__(512) void attn_kernel(const short* __restrict__ qb,
                            const short* __restrict__ kb,
                            const short* __restrict__ vb,
                            float* __restrict__ pO,
                            float* __restrict__ pMS) {
  __shared__ __align__(16) short Ksm[64 * 64];       // [key][d], chunk^=(key&7)
  __shared__ __align__(16) short Vsm[64 * 64];       // [d][key], chunk^=(d&7)
  __shared__ __align__(16) short Psm[8][32 * 64];    // per-wave P, chunk^=(row&7)
  int blk = blockIdx.x;
  int sp = blk & (SPLIT - 1), bh = blk >> 3;
  int t = threadIdx.x, wave = t >> 6, lane = t & 63;
  int lr = lane & 15, lg = lane >> 4;
  int q0 = wave * 32;
  const short* qptr = qb + (size_t)bh * Mm * HDd;
  short8 qf[2][2];
#pragma unroll
  for (int mi = 0; mi < 2; mi++)
#pragma unroll
    for (int ks = 0; ks < 2; ks++)
      qf[mi][ks] = *(const short8*)(qptr + (size_t)(q0 + mi * 16 + lr) * HDd + ks * 32 + lg * 8);
  f32x4 accO[2][4] = {};
  float mrow[2][4], srow[2][4];
#pragma unroll
  for (int mi = 0; mi < 2; mi++)
#pragma unroll
    for (int r = 0; r < 4; r++) { mrow[mi][r] = -1e30f; srow[mi][r] = 0.0f; }
  const short* kbase = kb + (size_t)bh * Ss * HDd;
  const short* vbase = vb + (size_t)bh * Ss * HDd;
  short* P = &Psm[wave][0];
  int tile0 = (sp * 68) >> 3, tile1 = ((sp + 1) * 68) >> 3;
  for (int tt = tile0; tt < tile1; tt++) {
    int kt = tt * 64;
    __syncthreads();
    {
      int r = t >> 3, c = t & 7;             // 512 threads, one 16B chunk each
      int cl = c ^ (r & 7);
      gload16(kbase + (size_t)(kt + r) * HDd + cl * 8, Ksm + t * 8);
      short8 vv = *(const short8*)(vbase + (size_t)(kt + r) * HDd + c * 8);
#pragma unroll
      for (int e = 0; e < 8; e++) {
        int d = c * 8 + e;
        Vsm[d * 64 + (((r >> 3) ^ (d & 7)) * 8) + (r & 7)] = vv[e];
      }
    }
    __syncthreads();
    // S = Q @ K^T
    f32x4 accS[2][4] = {};
#pragma unroll
    for (int ks = 0; ks < 2; ks++) {
      short8 bk[4];
#pragma unroll
      for (int ji = 0; ji < 4; ji++) {
        int j = ji * 16 + lr;
        int cd = ks * 4 + lg;
        bk[ji] = *(const short8*)(Ksm + j * 64 + ((cd ^ (j & 7)) * 8));
      }
#pragma unroll
      for (int mi = 0; mi < 2; mi++)
#pragma unroll
        for (int ji = 0; ji < 4; ji++)
          accS[mi][ji] = __builtin_amdgcn_mfma_f32_16x16x32_bf16(qf[mi][ks], bk[ji], accS[mi][ji], 0, 0, 0);
    }
    // online softmax (fp32, 16-lane reductions)
#pragma unroll
    for (int mi = 0; mi < 2; mi++)
#pragma unroll
      for (int r = 0; r < 4; r++) {
        float mx = fmaxf(fmaxf(accS[mi][0][r], accS[mi][1][r]),
                         fmaxf(accS[mi][2][r], accS[mi][3][r]));
#pragma unroll
        for (int o = 1; o < 16; o <<= 1) mx = fmaxf(mx, __shfl_xor(mx, o, 64));
        float mnew = fmaxf(mrow[mi][r], mx);
        float corr = __expf(mrow[mi][r] - mnew);
        mrow[mi][r] = mnew;
        float rs = 0.0f;
#pragma unroll
        for (int ji = 0; ji < 4; ji++) {
          float pv = __expf(accS[mi][ji][r] - mnew);
          accS[mi][ji][r] = pv;
          rs += pv;
        }
#pragma unroll
        for (int o = 1; o < 16; o <<= 1) rs += __shfl_xor(rs, o, 64);
        srow[mi][r] = srow[mi][r] * corr + rs;
#pragma unroll
        for (int di = 0; di < 4; di++) accO[mi][di][r] *= corr;
      }
    // P -> LDS (wave-private, swizzled), bf16
#pragma unroll
    for (int mi = 0; mi < 2; mi++)
#pragma unroll
      for (int ji = 0; ji < 4; ji++)
#pragma unroll
        for (int r = 0; r < 4; r++) {
          int row = mi * 16 + lg * 4 + r;
          int col = ji * 16 + lr;
          P[row * 64 + (((col >> 3) ^ (row & 7)) * 8) + (col & 7)] = f2bf(accS[mi][ji][r]);
        }
    // O += P @ V
#pragma unroll
    for (int ks = 0; ks < 2; ks++) {
      short8 pa[2], bvv[4];
#pragma unroll
      for (int mi = 0; mi < 2; mi++) {
        int row = mi * 16 + lr;
        int ck = ks * 4 + lg;
        pa[mi] = *(const short8*)(P + row * 64 + ((ck ^ (row & 7)) * 8));
      }
#pragma unroll
      for (int di = 0; di < 4; di++) {
        int d = di * 16 + lr;
        int ck = ks * 4 + lg;
        bvv[di] = *(const short8*)(Vsm + d * 64 + ((ck ^ (d & 7)) * 8));
      }
#pragma unroll
      for (int mi = 0; mi < 2; mi++)
#pragma unroll
        for (int di = 0; di < 4; di++)
          accO[mi][di] = __builtin_amdgcn_mfma_f32_16x16x32_bf16(pa[mi], bvv[di], accO[mi][di], 0, 0, 0);
    }
  }
  // write split partials (unnormalized O in fp32 + per-row m,s)
  size_t base = (size_t)blk * 256;
#pragma unroll
  for (int mi = 0; mi < 2; mi++)
#pragma unroll
    for (int r = 0; r < 4; r++) {
      int m = q0 + mi * 16 + lg * 4 + r;
      if (lr == 0) {
        pMS[(base + m) * 2]     = mrow[mi][r];
        pMS[(base + m) * 2 + 1] = srow[mi][r];
      }
#pragma unroll
      for (int di = 0; di < 4; di++)
        pO[(base + m) * 64 + di * 16 + lr] = accO[mi][di][r];
    }
}

// ---------------- combine the SPLIT partials ----------------
__global__ void attn_combine(const float* __restrict__ pO, const float* __restrict__ pMS,
                             short* __restrict__ ob) {
  int t = threadIdx.x;
  int row = blockIdx.x * 4 + (t >> 6);       // over B*H*M = 32768
  int bh = row >> 8, m = row & 255;
  int d = t & 63;
  float mv[SPLIT], sv[SPLIT];
  float mx = -1e30f;
#pragma unroll
  for (int s = 0; s < SPLIT; s++) {
    size_t rbase = ((size_t)(bh * SPLIT + s) * 256 + m);
    mv[s] = pMS[rbase * 2];
    sv[s] = pMS[rbase * 2 + 1];
    mx = fmaxf(mx, mv[s]);
  }
  float den = 0.0f, acc = 0.0f;
#pragma unroll
  for (int s = 0; s < SPLIT; s++) {
    float wgt = __expf(mv[s] - mx);
    den += wgt * sv[s];
    acc += wgt * pO[((size_t)(bh * SPLIT + s) * 256 + m) * 64 + d];
  }
  int b = bh >> 4, h = bh & 15;
  ob[((size_t)(b * Mm + m)) * INNERd + h * HDd + d] = f2bf(acc / den);
}

extern "C" void kernel_launch(void* const* d_in, const int* in_sizes, int n_in,
                              void* d_out, int out_size, void* d_ws, size_t ws_size,
                              hipStream_t stream) {
  const float* x    = (const float*)d_in[0];
  const float* lat  = (const float*)d_in[1];
  const float* lnxw = (const float*)d_in[2];
  const float* lnxb = (const float*)d_in[3];
  const float* lnlw = (const float*)d_in[4];
  const float* lnlb = (const float*)d_in[5];
  const float* Wq   = (const float*)d_in[6];
  const float* Wkv  = (const float*)d_in[7];
  const float* Wo   = (const float*)d_in[8];
  char* w = (char*)d_ws;
  const size_t MB = 1048576;
  short* Wqkvt = (short*)(w + 0 * MB);     // 6 MB: rows 0-1023 = Wq^T, 1024-3071 = Wkv^T
  short* Wot   = (short*)(w + 6 * MB);     // 2 MB
  short* xn    = (short*)(w + 8 * MB);     // 64 MB (reused as pO by attn)
  short* lnr   = (short*)(w + 72 * MB);    // 4 MB (reused as pMS by attn)
  short* qbuf  = (short*)(w + 76 * MB);    // 4 MB
  short* kbuf  = (short*)(w + 80 * MB);    // 68 MB
  short* vbuf  = (short*)(w + 148 * MB);   // 68 MB
  short* aout  = (short*)(w + 216 * MB);   // 4 MB
  float* pO    = (float*)(w + 8 * MB);     // 64 MB, aliases xn (dead by attn time)
  float* pMS   = (float*)(w + 72 * MB);    // 2 MB, aliases lnr (dead by attn time)

  ln_bf16_kernel<<<dim3(Bb * Nn), dim3(256), 0, stream>>>(x, lnxw, lnxb, xn);
  ln_bf16_kernel<<<dim3(Bb * Mm), dim3(256), 0, stream>>>(lat, lnlw, lnlb, lnr);
  wconv_kernel<<<dim3(32, 32), dim3(32, 8), 0, stream>>>(Wq, Wqkvt, 1024, 1024);
  wconv_kernel<<<dim3(64, 32), dim3(32, 8), 0, stream>>>(Wkv, Wqkvt + (size_t)1024 * 1024, 1024, 2048);
  wconv_kernel<<<dim3(32, 32), dim3(32, 8), 0, stream>>>(Wo, Wot, 1024, 1024);
  // kv_x = xn @ Wkv -> k/v scatter, fused RoPE.  grid: 128 rowp x 8 colp = 1024
  gemm8_kernel<2><<<dim3(1024), dim3(512), 0, stream>>>(
      xn, Wqkvt + (size_t)1024 * 1024, (short*)nullptr, kbuf, vbuf, 8);
  // fused q + kv_l = lnr @ [Wq|Wkv].  grid: 8 rowp x 12 colp = 96
  gemm8_kernel<4><<<dim3(96), dim3(512), 0, stream>>>(
      lnr, Wqkvt, qbuf, kbuf, vbuf, 12);
  // flash attention with KV-split 8 + combine
  attn_kernel<<<dim3(Bb * Hh * SPLIT), dim3(512), 0, stream>>>(qbuf, kbuf, vbuf, pO, pMS);
  attn_combine<<<dim3(Bb * Hh * Mm / 4), dim3(256), 0, stream>>>(pO, pMS, aout);
  // out = aout @ Wo (fp32)
  gemm_out_kernel<<<dim3(8, 16), dim3(256), 0, stream>>>(aout, Wot, (float*)d_out, 1024, 1024);
}